// Round 1
// baseline (5249.433 us; speedup 1.0000x reference)
//
#include <hip/hip_runtime.h>
#include <math.h>

#define D_DIM 256
#define R_STG 8
#define K_CB  1024
#define MT    64      // rows per block
#define NT    512     // threads per block (8 waves)
#define NKC   512     // k-chunk size (== NT for staging map)
#define DC    16      // d-chunk staged in LDS
#define NKP   516     // padded k stride (multiple of 4, bank-friendly)

// Swizzled transposed residual layout: [d][m], m-bits 3..5 XOR'd with d&7
// so column writes (fixed m, varying d) spread across banks while keeping
// 8 consecutive m contiguous for b128 reads.
__device__ __forceinline__ int ridx(int d, int m) {
  return d * MT + (m ^ ((d & 7) << 3));
}

__global__ void rvq_init(float* __restrict__ out, size_t loss_off, int n) {
  int i = blockIdx.x * blockDim.x + threadIdx.x;
  if (i < n) out[loss_off + i] = 0.0f;
}

__global__ __launch_bounds__(NT)
void rvq_fused(const float* __restrict__ z, const float* __restrict__ embed,
               float* __restrict__ out, int B,
               size_t zq_off, size_t res_off, size_t loss_off, size_t usage_off)
{
  __shared__ float Rres[D_DIM * MT];      // 64 KB residual tile (transposed, swizzled)
  __shared__ float Es[DC * NKP];          // 33 KB embed chunk, [d][k] transposed
  __shared__ float e2s[NKC];
  __shared__ float x2s[MT];
  __shared__ float px[MT][8];
  __shared__ int   codeS[MT];
  __shared__ float redv[8][8][8];         // [wave][tid_m][im]
  __shared__ int   redk[8][8][8];
  __shared__ float lossS[8];

  const int t = threadIdx.x;
  const int row0 = blockIdx.x * MT;
  const int tid_m = t & 7;        // 8 row-groups of 8 rows
  const int tid_k = t >> 3;       // 64 k-groups of 8 k

  // ---- load z tile into LDS residual ----
  for (int idx = t; idx < MT * D_DIM; idx += NT) {
    int m = idx >> 8;
    int d = idx & (D_DIM - 1);
    Rres[ridx(d, m)] = z[(size_t)(row0 + m) * D_DIM + d];
  }
  __syncthreads();

  // ---- initial x2 per row (sequential-d order) ----
  {
    int m = t & (MT - 1), q = t >> 6;
    float s = 0.0f;
    for (int j = 0; j < 32; ++j) { float v = Rres[ridx(q * 32 + j, m)]; s += v * v; }
    px[m][q] = s;
  }
  __syncthreads();
  if (t < MT) { float s = 0.0f; for (int q = 0; q < 8; ++q) s += px[t][q]; x2s[t] = s; }
  __syncthreads();

  for (int r = 0; r < R_STG; ++r) {
    const float* E = embed + (size_t)r * K_CB * D_DIM;
    float bv[8]; int bk[8];
#pragma unroll
    for (int i = 0; i < 8; ++i) { bv[i] = INFINITY; bk[i] = 0; }

    for (int kc = 0; kc < K_CB; kc += NKC) {
      float acc[8][8];
#pragma unroll
      for (int i = 0; i < 8; ++i)
#pragma unroll
        for (int j = 0; j < 8; ++j) acc[i][j] = 0.0f;
      float e2loc = 0.0f;   // this thread stages k = kc + t; e2 in sequential d order

      for (int dc = 0; dc < D_DIM; dc += DC) {
        __syncthreads();    // protect Es from readers of previous chunk
        {
          const float* src = E + (size_t)(kc + t) * D_DIM + dc;
#pragma unroll
          for (int jj = 0; jj < DC; jj += 4) {
            float4 v = *reinterpret_cast<const float4*>(src + jj);
            Es[(jj + 0) * NKP + t] = v.x;
            Es[(jj + 1) * NKP + t] = v.y;
            Es[(jj + 2) * NKP + t] = v.z;
            Es[(jj + 3) * NKP + t] = v.w;
            e2loc += v.x * v.x;
            e2loc += v.y * v.y;
            e2loc += v.z * v.z;
            e2loc += v.w * v.w;
          }
        }
        __syncthreads();
#pragma unroll
        for (int dd = 0; dd < DC; ++dd) {
          int d = dc + dd;                        // (d&7) == (dd&7) since DC=16
          const float* rp = &Rres[d * MT + ((tid_m ^ (dd & 7)) << 3)];
          const float* ep = &Es[dd * NKP + (tid_k << 3)];
          float4 ra = *reinterpret_cast<const float4*>(rp);
          float4 rb = *reinterpret_cast<const float4*>(rp + 4);
          float4 ea = *reinterpret_cast<const float4*>(ep);
          float4 eb = *reinterpret_cast<const float4*>(ep + 4);
          float rm[8] = {ra.x, ra.y, ra.z, ra.w, rb.x, rb.y, rb.z, rb.w};
          float ek[8] = {ea.x, ea.y, ea.z, ea.w, eb.x, eb.y, eb.z, eb.w};
#pragma unroll
          for (int i = 0; i < 8; ++i)
#pragma unroll
            for (int j = 0; j < 8; ++j)
              acc[i][j] = fmaf(rm[i], ek[j], acc[i][j]);
        }
      }
      __syncthreads();
      e2s[t] = e2loc;
      __syncthreads();

      // dist = fl(fl(x2 + e2) - fl(2*dot)); 2*dot is exact (power of 2)
#pragma unroll
      for (int im = 0; im < 8; ++im) {
        float x2 = x2s[tid_m * 8 + im];
#pragma unroll
        for (int j = 0; j < 8; ++j) {
          float e2 = e2s[(tid_k << 3) + j];
          float s = x2 + e2;
          float m2 = 2.0f * acc[im][j];
          float dist = s - m2;
          // ascending-k scan: strict < keeps first-index semantics in-thread
          if (dist < bv[im]) { bv[im] = dist; bk[im] = kc + (tid_k << 3) + j; }
        }
      }
    } // kc

    // ---- argmin reduce over 64 k-groups: in-wave (xor 8,16,32) then LDS ----
#pragma unroll
    for (int off = 8; off < 64; off <<= 1) {
#pragma unroll
      for (int im = 0; im < 8; ++im) {
        float ov = __shfl_xor(bv[im], off);
        int   ok = __shfl_xor(bk[im], off);
        if (ov < bv[im] || (ov == bv[im] && ok < bk[im])) { bv[im] = ov; bk[im] = ok; }
      }
    }
    {
      int wave = t >> 6, lane = t & 63;
      if (lane < 8) {
#pragma unroll
        for (int im = 0; im < 8; ++im) { redv[wave][lane][im] = bv[im]; redk[wave][lane][im] = bk[im]; }
      }
    }
    __syncthreads();
    if (t < MT) {
      int tm = t >> 3, im = t & 7;
      float v = redv[0][tm][im]; int k = redk[0][tm][im];
#pragma unroll
      for (int w = 1; w < 8; ++w) {
        float v2 = redv[w][tm][im]; int k2 = redk[w][tm][im];
        if (v2 < v || (v2 == v && k2 < k)) { v = v2; k = k2; }
      }
      codeS[t] = k;
      out[(size_t)(row0 + t) * R_STG + r] = (float)k;         // codes as f32
      atomicAdd(&out[usage_off + (size_t)r * K_CB + k], 0x1p-16f);  // exact 1/65536
    }
    __syncthreads();

    // ---- residual update (same sequential subtraction as the reference scan)
    //      + new x2 in sequential-d order ----
    {
      int m = t & (MT - 1), q = t >> 6;       // 8 threads per row, 32 d each
      const float* erow = E + (size_t)codeS[m] * D_DIM + q * 32;
      float s = 0.0f;
#pragma unroll
      for (int j = 0; j < 32; j += 4) {
        float4 ev = *reinterpret_cast<const float4*>(erow + j);
        int d0 = q * 32 + j;
        float n0 = Rres[ridx(d0 + 0, m)] - ev.x; Rres[ridx(d0 + 0, m)] = n0; s += n0 * n0;
        float n1 = Rres[ridx(d0 + 1, m)] - ev.y; Rres[ridx(d0 + 1, m)] = n1; s += n1 * n1;
        float n2 = Rres[ridx(d0 + 2, m)] - ev.z; Rres[ridx(d0 + 2, m)] = n2; s += n2 * n2;
        float n3 = Rres[ridx(d0 + 3, m)] - ev.w; Rres[ridx(d0 + 3, m)] = n3; s += n3 * n3;
      }
      px[m][q] = s;
    }
    __syncthreads();
    if (t < MT) { float s = 0.0f; for (int q = 0; q < 8; ++q) s += px[t][q]; x2s[t] = s; }
    __syncthreads();
  } // stage

  // ---- epilogue: z_q = z - residual, residual, loss partial ----
  float lsum = 0.0f;
  for (int idx = t; idx < MT * D_DIM; idx += NT) {
    int m = idx >> 8;
    int d = idx & (D_DIM - 1);
    float res = Rres[ridx(d, m)];
    size_t g = (size_t)(row0 + m) * D_DIM + d;
    float zz = z[g];
    out[zq_off + g]  = zz - res;
    out[res_off + g] = res;
    lsum += res * res;
  }
#pragma unroll
  for (int off = 32; off > 0; off >>= 1) lsum += __shfl_down(lsum, off);
  if ((t & 63) == 0) lossS[t >> 6] = lsum;
  __syncthreads();
  if (t == 0) {
    float s = 0.0f;
#pragma unroll
    for (int w = 0; w < 8; ++w) s += lossS[w];
    atomicAdd(&out[loss_off], s * (1.0f / ((float)B * (float)D_DIM)));
  }
}

extern "C" void kernel_launch(void* const* d_in, const int* in_sizes, int n_in,
                              void* d_out, int out_size, void* d_ws, size_t ws_size,
                              hipStream_t stream) {
  const float* z     = (const float*)d_in[0];
  const float* embed = (const float*)d_in[1];
  float* out = (float*)d_out;
  int B = in_sizes[0] / D_DIM;

  size_t zq_off    = (size_t)B * R_STG;
  size_t res_off   = zq_off + (size_t)B * D_DIM;
  size_t loss_off  = res_off + (size_t)B * D_DIM;
  size_t usage_off = loss_off + 1;
  int tail_n = 1 + R_STG * K_CB;   // loss + usage

  rvq_init<<<(tail_n + 255) / 256, 256, 0, stream>>>(out, loss_off, tail_n);
  rvq_fused<<<B / MT, NT, 0, stream>>>(z, embed, out, B,
                                       zq_off, res_off, loss_off, usage_off);
}